// Round 16
// baseline (348.025 us; speedup 1.0000x reference)
//
#include <hip/hip_runtime.h>
#include <hip/hip_bf16.h>
#include <math.h>

#define B_ 8
#define T1_ 32
#define T2_ 32
#define T3_ 16
#define D_ 512
#define L_ 20
#define DL_ 128
#define M_ (B_*T1_*T2_*T3_)   // 131072
#define ROWS 64               // rows per block

// workspace layout (float offsets)
#define WS_FS   0        // B*DL f32 = 1024
#define WS_SB   1024     // B*L f32 = 160
#define WS_WDB  1184     // Wc_down bf16 [128][512]
#define WS_WUB  33952    // Wc_up bf16 [512][128]
#define WS_KQB  66720    // kq bf16 [B][32][128] (rows>=20 zero)
#define WS_FWT  83104    // fw^T bf16 [B][128][32] (cols>=20 zero)
#define WS_FBM  99488    // fbar_m f32 [B][T1][T2][D] = 4194304

typedef __attribute__((ext_vector_type(8))) short short8_t;
typedef __attribute__((ext_vector_type(4))) float f32x4;

__device__ __forceinline__ unsigned pkcvt(float a, float b) {
  float2 v; v.x = a; v.y = b;
  __hip_bfloat162 h = __float22bfloat162_rn(v);
  unsigned r;
  __builtin_memcpy(&r, &h, sizeof(r));
  return r;
}
__device__ __forceinline__ unsigned short f2b(float f) {
  __hip_bfloat16 h = __float2bfloat16(f);
  unsigned short r;
  __builtin_memcpy(&r, &h, sizeof(r));
  return r;
}
__device__ __forceinline__ float b2f(short s) {
  return __uint_as_float(((unsigned)(unsigned short)s) << 16);
}
__device__ __forceinline__ int4 pack8(float4 a, float4 b) {
  int4 p;
  p.x = (int)pkcvt(a.x, a.y); p.y = (int)pkcvt(a.z, a.w);
  p.z = (int)pkcvt(b.x, b.y); p.w = (int)pkcvt(b.z, b.w);
  return p;
}

// ---------------------------------------------------------------------------
// K0: fbar_m gate (all threads) + weight fp32->bf16 + kqb/fwtb zeroing
// ---------------------------------------------------------------------------
__global__ __launch_bounds__(256) void k0_prep(
    const float* __restrict__ Wd, const float* __restrict__ Wu,
    const float* __restrict__ f_m, const float* __restrict__ f_s,
    unsigned short* __restrict__ wdb, unsigned short* __restrict__ wub,
    unsigned short* __restrict__ kqb, unsigned short* __restrict__ fwtb,
    float* __restrict__ fbm) {
  int i = blockIdx.x * 256 + threadIdx.x;      // 0..1048575
  {
    float4 m = ((const float4*)f_m)[i];
    int e = i * 4; int b = e >> 19; int d0 = e & 511;
    float4 s = *(const float4*)(f_s + (size_t)b*D_ + d0);
    float4 g;
    g.x = m.x/(1.f + __expf(-m.x*s.x));
    g.y = m.y/(1.f + __expf(-m.y*s.y));
    g.z = m.z/(1.f + __expf(-m.z*s.z));
    g.w = m.w/(1.f + __expf(-m.w*s.w));
    ((float4*)fbm)[i] = g;
  }
  if (i < 16384) {
    float4 v = ((const float4*)Wd)[i];
    uint2 h; h.x = pkcvt(v.x, v.y); h.y = pkcvt(v.z, v.w);
    ((uint2*)wdb)[i] = h;
  } else if (i < 32768) {
    int q = i - 16384;
    float4 v = ((const float4*)Wu)[q];
    uint2 h; h.x = pkcvt(v.x, v.y); h.y = pkcvt(v.z, v.w);
    ((uint2*)wub)[q] = h;
  }
  if (i < 32768) { kqb[i] = 0; fwtb[i] = 0; }
}

// ---------------------------------------------------------------------------
// K1: tiny projections -> kqb (bf16), fwtb (bf16 transposed), fs/sb (f32)
// ---------------------------------------------------------------------------
__global__ __launch_bounds__(128) void k1_small(
    const float* __restrict__ f_w, const float* __restrict__ f_s,
    const float* __restrict__ Ww, const float* __restrict__ bw,
    const float* __restrict__ Ws, const float* __restrict__ bs,
    const float* __restrict__ Wq, const float* __restrict__ bq,
    const float* __restrict__ Wk, const float* __restrict__ bk,
    unsigned short* __restrict__ kqb, unsigned short* __restrict__ fwtb,
    float* __restrict__ ws) {
  const int bl = blockIdx.x;
  const int b = bl / L_, l = bl % L_;
  const int d = threadIdx.x;
  __shared__ float s_fw[DL_];
  __shared__ float s_k[DL_];
  {
    const float* x = f_w + (size_t)(b*L_+l)*D_;
    const float* w = Ww + (size_t)d*D_;
    float acc = 0.f;
    for (int i = 0; i < D_; i += 4)
      acc += x[i]*w[i] + x[i+1]*w[i+1] + x[i+2]*w[i+2] + x[i+3]*w[i+3];
    acc += bw[d];
    s_fw[d] = acc;
    fwtb[((size_t)(b*DL_ + d))*32 + l] = f2b(acc);
  }
  if (l == 0) {
    const float* x = f_s + (size_t)b*D_;
    const float* w = Ws + (size_t)d*D_;
    float acc = 0.f;
    for (int i = 0; i < D_; i += 4)
      acc += x[i]*w[i] + x[i+1]*w[i+1] + x[i+2]*w[i+2] + x[i+3]*w[i+3];
    ws[WS_FS + b*DL_ + d] = acc + bs[d];
  }
  __syncthreads();
  {
    const float* w = Wk + (size_t)d*DL_;
    float acc = 0.f;
    for (int i = 0; i < DL_; ++i) acc += s_fw[i]*w[i];
    s_k[d] = acc + bk[d];
  }
  __syncthreads();
  {
    float acc = 0.f;
    for (int c = 0; c < DL_; ++c) acc += s_k[c] * Wq[c*DL_ + d];
    kqb[((size_t)(b*32 + l))*DL_ + d] = f2b(acc);
  }
  if (d == 0) {
    float acc = 0.f;
    for (int c = 0; c < DL_; ++c) acc += bq[c]*s_k[c];
    ws[WS_SB + b*L_ + l] = acc;
  }
}

// ---------------------------------------------------------------------------
// K2: fused per 64-row tile, 512 threads (8 waves). 38 KB LDS -> 4 blocks/CU.
// Up-GEMM: A=Wu fragments DIRECT from global (L2-hot), zero barriers.
// ---------------------------------------------------------------------------
// Region A: 0..16384
#define WD_B   0                 // down: Wd chunk [128][128B] swz
#define SFCH_B 0                 // after down: f_c_hat bf16 [64][256B] swz
// Region B: 16384..32768
#define FC_B   16384             // down: f_c chunk [64][128B] swz
#define ATTN_F 16384             // phase2: attn f32 [64][21] = 5376B
#define ATB_B  22528             // phase2.5-3: attn bf16 [64][128B] swz
#define FCQ_B  16384             // phase3+: f_cq/f_cc_hat bf16 [64][256B] swz
// Region C: 32768..38912
#define AC_B   32768             // A_c f32 [64][17] = 4352
#define FS_B   37120             // f_s_hat f32 [128]
#define SB_B   37632             // sb f32 [20]
#define SMEM_B 38912

__global__ __launch_bounds__(512, 8) void k2_fused(
    const float* __restrict__ f_c, const unsigned short* __restrict__ wdb,
    const unsigned short* __restrict__ wub,
    const unsigned short* __restrict__ kqb, const unsigned short* __restrict__ fwtb,
    const float* __restrict__ bc_down, const float* __restrict__ bc_up,
    const float* __restrict__ fbm,
    const float* __restrict__ ws, float* __restrict__ out) {
  __shared__ __align__(16) char smb[SMEM_B];
  float* sAttn = (float*)(smb + ATTN_F);
  float* sAc   = (float*)(smb + AC_B);
  float* sFs   = (float*)(smb + FS_B);
  float* sSb   = (float*)(smb + SB_B);

  const int t = threadIdx.x;            // 0..511
  const int row0 = blockIdx.x * ROWS;
  const int b = row0 >> 14;
  const int lane = t & 63, w = t >> 6;  // 8 waves
  const int l15 = lane & 15, l4 = lane >> 4;
  const float inv_sqrt_dl = 0.08838834764831843f;
  const f32x4 z4 = {0.f, 0.f, 0.f, 0.f};

  // staging coords
  const int sd_r  = t >> 3;             // 0..63   (FC: 1 int4/thread)
  const int sd_k8 = (t & 7) * 8;
  const int sd_swz = (sd_k8 * 2) ^ ((sd_r & 7) << 4);

  // ---------------- down GEMM: single-buffered, 2 barriers/chunk -----------
  f32x4 dacc[4];
  #pragma unroll
  for (int rt = 0; rt < 4; ++rt) dacc[rt] = z4;

  {
    const int ad = w * 16 + l15;                 // A row (d) for this wave
    const int aswz = (ad & 7) << 4;
    for (int ch = 0; ch < 8; ++ch) {
      const int kc = ch * 64;
      #pragma unroll
      for (int i = 0; i < 2; ++i) {
        const int idx = t + i*512;
        const int r = idx >> 3, k8 = (idx & 7) * 8;
        *(int4*)(smb + WD_B + r*128 + ((k8*2) ^ ((r & 7) << 4))) =
          *(const int4*)(wdb + (size_t)r*D_ + kc + k8);
      }
      {
        const float* src = f_c + (size_t)(row0 + sd_r)*D_ + kc + sd_k8;
        float4 v0 = *(const float4*)src;
        float4 v1 = *(const float4*)(src + 4);
        *(int4*)(smb + FC_B + sd_r*128 + sd_swz) = pack8(v0, v1);
      }
      __syncthreads();
      #pragma unroll
      for (int ks = 0; ks < 2; ++ks) {
        short8_t afrag = *(const short8_t*)(smb + WD_B + ad*128 +
                          ((ks*64 + l4*16) ^ aswz));
        #pragma unroll
        for (int rt = 0; rt < 4; ++rt) {
          const int rr = rt*16 + l15;
          short8_t bfrag = *(const short8_t*)(smb + FC_B + rr*128 +
                            ((ks*64 + l4*16) ^ ((rr & 7) << 4)));
          dacc[rt] = __builtin_amdgcn_mfma_f32_16x16x32_bf16(afrag, bfrag, dacc[rt], 0, 0, 0);
        }
      }
      __syncthreads();
    }
  }
  // writeout f_c_hat bf16 swz into region A (WD dead) + stage fs/sb
  {
    const int d0 = w*16 + l4*4;
    float4 bias = *(const float4*)(bc_down + d0);
    #pragma unroll
    for (int rt = 0; rt < 4; ++rt) {
      const int rr = rt*16 + l15;
      uint2 pw;
      pw.x = pkcvt(dacc[rt][0] + bias.x, dacc[rt][1] + bias.y);
      pw.y = pkcvt(dacc[rt][2] + bias.z, dacc[rt][3] + bias.w);
      *(uint2*)(smb + SFCH_B + rr*256 + ((d0*2) ^ ((rr & 7) << 4))) = pw;
    }
  }
  if (t < 32) *(float4*)(sFs + t*4) = *(const float4*)(ws + WS_FS + b*DL_ + t*4);
  if (t < L_) sSb[t] = ws[WS_SB + b*L_ + t];
  __syncthreads();

  // ---------------- phase2: scores via MFMA; kq frags direct-global --------
  {
    const int lt = w & 1, rt2 = w >> 1;       // l-tile(0..1), r-tile(0..3)
    const int arow = lt*16 + l15;
    const int brow = rt2*16 + l15;
    const unsigned short* kqrow = kqb + (size_t)(b*32 + arow)*DL_;
    f32x4 sacc = z4;
    #pragma unroll
    for (int ks = 0; ks < 4; ++ks) {
      short8_t af = *(const short8_t*)(kqrow + ks*32 + l4*8);
      short8_t bf = *(const short8_t*)(smb + SFCH_B + brow*256 +
                     ((ks*64 + l4*16) ^ ((brow & 7) << 4)));
      sacc = __builtin_amdgcn_mfma_f32_16x16x32_bf16(af, bf, sacc, 0, 0, 0);
    }
    const int r2 = rt2*16 + l15;
    #pragma unroll
    for (int reg = 0; reg < 4; ++reg) {
      const int lval = lt*16 + l4*4 + reg;
      if (lval < L_) sAttn[r2*21 + lval] = (sacc[reg] + sSb[lval]) * inv_sqrt_dl;
    }
  }
  __syncthreads();
  if (t < ROWS) {                              // softmax over L
    float* srow = sAttn + t*21;
    float m = -1e30f;
    for (int l = 0; l < L_; ++l) m = fmaxf(m, srow[l]);
    float sum = 0.f;
    for (int l = 0; l < L_; ++l) { float e = __expf(srow[l]-m); srow[l] = e; sum += e; }
    float inv = 1.f/sum;
    for (int l = 0; l < L_; ++l) srow[l] *= inv;
  }
  __syncthreads();
  { // pack attn -> bf16 [64][128B] swz at ATB (disjoint from sAttn)
    const int r = t >> 3, k8 = (t & 7) * 8;
    int4 v = {0,0,0,0};
    if (k8 < L_) {
      float vv[8];
      #pragma unroll
      for (int e = 0; e < 8; ++e) {
        const int l = k8 + e;
        vv[e] = (l < L_) ? sAttn[r*21 + l] : 0.f;
      }
      v.x = (int)pkcvt(vv[0], vv[1]);
      v.y = (int)pkcvt(vv[2], vv[3]);
      v.z = (int)pkcvt(vv[4], vv[5]);
      v.w = (int)pkcvt(vv[6], vv[7]);
    }
    *(int4*)(smb + ATB_B + r*128 + ((k8*2) ^ ((r & 7) << 4))) = v;
  }
  __syncthreads();
  // ---------------- phase3: f_caq via MFMA; fwT frags direct-global --------
  {
    f32x4 cacc[4];
    #pragma unroll
    for (int rt = 0; rt < 4; ++rt) cacc[rt] = z4;
    const int arow = w*16 + l15;               // fwT row (d)
    short8_t af = *(const short8_t*)(fwtb + (size_t)(b*DL_ + arow)*32 + l4*8);
    short8_t bf0 = *(const short8_t*)(smb + ATB_B + (0*16 + l15)*128 +
                    ((l4*16) ^ (((0*16 + l15) & 7) << 4)));
    short8_t bf1 = *(const short8_t*)(smb + ATB_B + (1*16 + l15)*128 +
                    ((l4*16) ^ (((1*16 + l15) & 7) << 4)));
    short8_t bf2 = *(const short8_t*)(smb + ATB_B + (2*16 + l15)*128 +
                    ((l4*16) ^ (((2*16 + l15) & 7) << 4)));
    short8_t bf3 = *(const short8_t*)(smb + ATB_B + (3*16 + l15)*128 +
                    ((l4*16) ^ (((3*16 + l15) & 7) << 4)));
    cacc[0] = __builtin_amdgcn_mfma_f32_16x16x32_bf16(af, bf0, cacc[0], 0, 0, 0);
    cacc[1] = __builtin_amdgcn_mfma_f32_16x16x32_bf16(af, bf1, cacc[1], 0, 0, 0);
    cacc[2] = __builtin_amdgcn_mfma_f32_16x16x32_bf16(af, bf2, cacc[2], 0, 0, 0);
    cacc[3] = __builtin_amdgcn_mfma_f32_16x16x32_bf16(af, bf3, cacc[3], 0, 0, 0);
    __syncthreads();            // all ATB reads complete before FCQ overwrite
    const int d0 = w*16 + l4*4;
    float4 fs4 = *(const float4*)(sFs + d0);
    #pragma unroll
    for (int rt = 0; rt < 4; ++rt) {
      const int r = rt*16 + l15;
      const int rs = (r & 7) << 4;
      ushort4 fh = *(const ushort4*)(smb + SFCH_B + r*256 + ((d0*2) ^ rs));
      uint2 pw;
      pw.x = pkcvt(b2f((short)fh.x)*(cacc[rt][0] + fs4.x),
                   b2f((short)fh.y)*(cacc[rt][1] + fs4.y));
      pw.y = pkcvt(b2f((short)fh.z)*(cacc[rt][2] + fs4.z),
                   b2f((short)fh.w)*(cacc[rt][3] + fs4.w));
      *(uint2*)(smb + FCQ_B + r*256 + ((d0*2) ^ rs)) = pw;
    }
  }
  __syncthreads();
  // ---------------- phase4: A_c Gram MFMA + wave-parallel softmax ----------
  if (w < 4) {
    const int zrow = w*16 + l15;
    f32x4 pacc = z4;
    #pragma unroll
    for (int ks = 0; ks < 4; ++ks) {
      short8_t fq = *(const short8_t*)(smb + FCQ_B + zrow*256 +
                     ((ks*64 + l4*16) ^ ((zrow & 7) << 4)));
      pacc = __builtin_amdgcn_mfma_f32_16x16x32_bf16(fq, fq, pacc, 0, 0, 0);
    }
    float p0[4], m[4], e[4], s[4];
    #pragma unroll
    for (int reg = 0; reg < 4; ++reg) p0[reg] = pacc[reg] * inv_sqrt_dl;
    #pragma unroll
    for (int reg = 0; reg < 4; ++reg) {
      m[reg] = p0[reg];
      m[reg] = fmaxf(m[reg], __shfl_xor(m[reg], 1));
      m[reg] = fmaxf(m[reg], __shfl_xor(m[reg], 2));
      m[reg] = fmaxf(m[reg], __shfl_xor(m[reg], 4));
      m[reg] = fmaxf(m[reg], __shfl_xor(m[reg], 8));
      e[reg] = __expf(p0[reg] - m[reg]);
      s[reg] = e[reg];
      s[reg] += __shfl_xor(s[reg], 1);
      s[reg] += __shfl_xor(s[reg], 2);
      s[reg] += __shfl_xor(s[reg], 4);
      s[reg] += __shfl_xor(s[reg], 8);
    }
    #pragma unroll
    for (int reg = 0; reg < 4; ++reg)
      sAc[(w*16 + l4*4 + reg)*17 + l15] = e[reg] / s[reg];
  }
  __syncthreads();
  // ---------------- phase5: f_cc_hat = A_c @ f_c_hat (VALU) -> FCQ ---------
  for (int p = t; p < ROWS*32; p += 512) {
    const int r = p >> 5, d4 = (p & 31)*4;
    const int g = r >> 4, z = r & 15;
    float ax = 0.f, ay = 0.f, az = 0.f, aw = 0.f;
    #pragma unroll
    for (int wq = 0; wq < 16; ++wq) {
      float a = sAc[(g*16+z)*17 + wq];
      const int fr = g*16 + wq;
      ushort4 fv = *(const ushort4*)(smb + SFCH_B + fr*256 + ((d4*2) ^ ((fr & 7) << 4)));
      ax += a*b2f((short)fv.x); ay += a*b2f((short)fv.y);
      az += a*b2f((short)fv.z); aw += a*b2f((short)fv.w);
    }
    uint2 pw;
    pw.x = pkcvt(ax, ay); pw.y = pkcvt(az, aw);
    *(uint2*)(smb + FCQ_B + r*256 + ((d4*2) ^ ((r & 7) << 4))) = pw;
  }
  __syncthreads();   // FCQ complete before up-GEMM reads it

  // ---------------- up GEMM: A=Wu direct from global (L2), 0 barriers ------
  {
    const int adr = (w & 3)*16 + l15;          // Wu row within chunk
    const int rbase = (w >> 2) * 32;
    const unsigned short* abase = wub + (size_t)adr*DL_ + l4*8;
    for (int ch = 0; ch < 8; ++ch) {
      const unsigned short* ap = abase + (size_t)ch*64*DL_;
      f32x4 uacc[2]; uacc[0] = z4; uacc[1] = z4;
      #pragma unroll
      for (int ks = 0; ks < 4; ++ks) {
        short8_t afrag = *(const short8_t*)(ap + ks*32);
        #pragma unroll
        for (int cf = 0; cf < 2; ++cf) {
          const int rr = rbase + cf*16 + l15;
          short8_t bfrag = *(const short8_t*)(smb + FCQ_B + rr*256 +
                            ((ks*64 + l4*16) ^ ((rr & 7) << 4)));
          uacc[cf] = __builtin_amdgcn_mfma_f32_16x16x32_bf16(afrag, bfrag, uacc[cf], 0, 0, 0);
        }
      }
      {
        const int d0 = ch*64 + (w & 3)*16 + l4*4;
        float4 bias = *(const float4*)(bc_up + d0);
        #pragma unroll
        for (int cf = 0; cf < 2; ++cf) {
          const int grow = row0 + rbase + cf*16 + l15;
          const size_t obase = (size_t)grow * D_;
          float4 fb4 = *(const float4*)(fbm + ((size_t)(grow >> 4))*D_ + d0);
          float4 fc4 = *(const float4*)(f_c + obase + d0);
          float4 o;
          o.x = uacc[cf][0] + bias.x + fc4.x + fb4.x;
          o.y = uacc[cf][1] + bias.y + fc4.y + fb4.y;
          o.z = uacc[cf][2] + bias.z + fc4.z + fb4.z;
          o.w = uacc[cf][3] + bias.w + fc4.w + fb4.w;
          *(float4*)(out + obase + d0) = o;
        }
      }
    }
  }
}

extern "C" void kernel_launch(void* const* d_in, const int* in_sizes, int n_in,
                              void* d_out, int out_size, void* d_ws, size_t ws_size,
                              hipStream_t stream) {
  (void)in_sizes; (void)n_in; (void)out_size; (void)ws_size;
  const float* f_c     = (const float*)d_in[0];
  const float* f_w     = (const float*)d_in[1];
  const float* f_s     = (const float*)d_in[2];
  const float* f_m     = (const float*)d_in[3];
  const float* Wc_down = (const float*)d_in[4];
  const float* bc_down = (const float*)d_in[5];
  const float* Ww      = (const float*)d_in[6];
  const float* bw      = (const float*)d_in[7];
  const float* Ws      = (const float*)d_in[8];
  const float* bs      = (const float*)d_in[9];
  const float* Wq      = (const float*)d_in[10];
  const float* bq      = (const float*)d_in[11];
  const float* Wk      = (const float*)d_in[12];
  const float* bk      = (const float*)d_in[13];
  const float* Wc_up   = (const float*)d_in[14];
  const float* bc_up   = (const float*)d_in[15];
  float* out = (float*)d_out;
  float* wsf = (float*)d_ws;
  unsigned short* wdb  = (unsigned short*)(wsf + WS_WDB);
  unsigned short* wub  = (unsigned short*)(wsf + WS_WUB);
  unsigned short* kqb  = (unsigned short*)(wsf + WS_KQB);
  unsigned short* fwtb = (unsigned short*)(wsf + WS_FWT);
  float* fbm = wsf + WS_FBM;

  hipLaunchKernelGGL(k0_prep, dim3(4096), dim3(256), 0, stream,
                     Wc_down, Wc_up, f_m, f_s, wdb, wub, kqb, fwtb, fbm);
  hipLaunchKernelGGL(k1_small, dim3(B_*L_), dim3(128), 0, stream,
                     f_w, f_s, Ww, bw, Ws, bs, Wq, bq, Wk, bk, kqb, fwtb, wsf);
  hipLaunchKernelGGL(k2_fused, dim3(M_/ROWS), dim3(512), 0, stream,
                     f_c, wdb, wub, kqb, fwtb, bc_down, bc_up, fbm, wsf, out);
}

// Round 18
// 232.729 us; speedup vs baseline: 1.4954x; 1.4954x over previous
//
#include <hip/hip_runtime.h>
#include <hip/hip_bf16.h>
#include <math.h>

#define B_ 8
#define T1_ 32
#define T2_ 32
#define T3_ 16
#define D_ 512
#define L_ 20
#define DL_ 128
#define M_ (B_*T1_*T2_*T3_)   // 131072
#define ROWS 64               // rows per block

// workspace layout (float offsets)
#define WS_FS   0        // B*DL f32 = 1024
#define WS_SB   1024     // B*L f32 = 160
#define WS_WDB  1184     // Wc_down bf16 [128][512]
#define WS_WUB  33952    // Wc_up bf16 [512][128]
#define WS_KQB  66720    // kq bf16 [B][32][128] (rows>=20 zero)
#define WS_FWT  83104    // fw^T bf16 [B][128][32] (cols>=20 zero)
#define WS_FBM  99488    // fbar_m f32 [B][T1][T2][D] = 4194304

typedef __attribute__((ext_vector_type(8))) short short8_t;
typedef __attribute__((ext_vector_type(4))) float f32x4;

__device__ __forceinline__ unsigned pkcvt(float a, float b) {
  float2 v; v.x = a; v.y = b;
  __hip_bfloat162 h = __float22bfloat162_rn(v);
  unsigned r;
  __builtin_memcpy(&r, &h, sizeof(r));
  return r;
}
__device__ __forceinline__ unsigned short f2b(float f) {
  __hip_bfloat16 h = __float2bfloat16(f);
  unsigned short r;
  __builtin_memcpy(&r, &h, sizeof(r));
  return r;
}
__device__ __forceinline__ float b2f(short s) {
  return __uint_as_float(((unsigned)(unsigned short)s) << 16);
}
__device__ __forceinline__ int4 pack8(float4 a, float4 b) {
  int4 p;
  p.x = (int)pkcvt(a.x, a.y); p.y = (int)pkcvt(a.z, a.w);
  p.z = (int)pkcvt(b.x, b.y); p.w = (int)pkcvt(b.z, b.w);
  return p;
}

// ---------------------------------------------------------------------------
// K0: blocks 0..4095: fbar_m gate + weight fp32->bf16 (NO kqb/fwtb writes)
//     blocks 4096..4255: k1 tiny projections; l==0 block also zeroes the
//     kqb/fwtb pad regions for its b (single-writer -> race-free)
// ---------------------------------------------------------------------------
__global__ __launch_bounds__(256) void k0_prep(
    const float* __restrict__ Wd, const float* __restrict__ Wu,
    const float* __restrict__ f_m, const float* __restrict__ f_s,
    const float* __restrict__ f_w,
    const float* __restrict__ Ww, const float* __restrict__ bw,
    const float* __restrict__ Ws, const float* __restrict__ bs,
    const float* __restrict__ Wq, const float* __restrict__ bq,
    const float* __restrict__ Wk, const float* __restrict__ bk,
    unsigned short* __restrict__ wdb, unsigned short* __restrict__ wub,
    unsigned short* __restrict__ kqb, unsigned short* __restrict__ fwtb,
    float* __restrict__ fbm, float* __restrict__ ws) {
  __shared__ float s_fw[DL_];
  __shared__ float s_k[DL_];

  if (blockIdx.x >= 4096) {
    // -------- k1 path: tiny projections --------
    const int bl = blockIdx.x - 4096;          // 0..159
    const int b = bl / L_, l = bl % L_;
    const bool act = threadIdx.x < DL_;
    const int d = threadIdx.x & (DL_ - 1);
    if (l == 0) {
      // zero pads for this b (only this block writes them)
      for (int p = threadIdx.x; p < 12*DL_; p += 256) {
        const int lz = 20 + (p >> 7), dz = p & 127;
        kqb[((size_t)(b*32 + lz))*DL_ + dz] = 0;
      }
      for (int p = threadIdx.x; p < DL_*12; p += 256) {
        const int dz = p / 12, lz = 20 + (p % 12);
        fwtb[((size_t)(b*DL_ + dz))*32 + lz] = 0;
      }
    }
    if (act) {
      const float* x = f_w + (size_t)(b*L_+l)*D_;
      const float* w = Ww + (size_t)d*D_;
      float acc = 0.f;
      for (int i = 0; i < D_; i += 4)
        acc += x[i]*w[i] + x[i+1]*w[i+1] + x[i+2]*w[i+2] + x[i+3]*w[i+3];
      acc += bw[d];
      s_fw[d] = acc;
      fwtb[((size_t)(b*DL_ + d))*32 + l] = f2b(acc);
      if (l == 0) {
        const float* xs = f_s + (size_t)b*D_;
        const float* wsp = Ws + (size_t)d*D_;
        float acc2 = 0.f;
        for (int i = 0; i < D_; i += 4)
          acc2 += xs[i]*wsp[i] + xs[i+1]*wsp[i+1] + xs[i+2]*wsp[i+2] + xs[i+3]*wsp[i+3];
        ws[WS_FS + b*DL_ + d] = acc2 + bs[d];
      }
    }
    __syncthreads();
    if (act) {
      const float* w = Wk + (size_t)d*DL_;
      float acc = 0.f;
      for (int i = 0; i < DL_; ++i) acc += s_fw[i]*w[i];
      s_k[d] = acc + bk[d];
    }
    __syncthreads();
    if (act) {
      float acc = 0.f;
      for (int c = 0; c < DL_; ++c) acc += s_k[c] * Wq[c*DL_ + d];
      kqb[((size_t)(b*32 + l))*DL_ + d] = f2b(acc);
      if (d == 0) {
        float acc2 = 0.f;
        for (int c = 0; c < DL_; ++c) acc2 += bq[c]*s_k[c];
        ws[WS_SB + b*L_ + l] = acc2;
      }
    }
    return;
  }

  // -------- gate + weight-convert path --------
  int i = blockIdx.x * 256 + threadIdx.x;      // 0..1048575
  {
    float4 m = ((const float4*)f_m)[i];
    int e = i * 4; int b = e >> 19; int d0 = e & 511;
    float4 s = *(const float4*)(f_s + (size_t)b*D_ + d0);
    float4 g;
    g.x = m.x/(1.f + __expf(-m.x*s.x));
    g.y = m.y/(1.f + __expf(-m.y*s.y));
    g.z = m.z/(1.f + __expf(-m.z*s.z));
    g.w = m.w/(1.f + __expf(-m.w*s.w));
    ((float4*)fbm)[i] = g;
  }
  if (i < 16384) {
    float4 v = ((const float4*)Wd)[i];
    uint2 h; h.x = pkcvt(v.x, v.y); h.y = pkcvt(v.z, v.w);
    ((uint2*)wdb)[i] = h;
  } else if (i < 32768) {
    int q = i - 16384;
    float4 v = ((const float4*)Wu)[q];
    uint2 h; h.x = pkcvt(v.x, v.y); h.y = pkcvt(v.z, v.w);
    ((uint2*)wub)[q] = h;
  }
}

// ---------------------------------------------------------------------------
// K2: fused per 64-row tile, 512 threads (8 waves). 38 KB LDS -> 4 blocks/CU
// (32 waves/CU). r15 structure exactly (verified best: 221.6 us).
// ---------------------------------------------------------------------------
// Region A: 0..16384
#define WD_B   0                 // down: Wd chunk [128][128B] swz
#define SFCH_B 0                 // after down: f_c_hat bf16 [64][256B] swz
#define WU_B   0                 // up: Wu chunk [64][256B] swz (after ph5)
// Region B: 16384..32768
#define FC_B   16384             // down: f_c chunk [64][128B] swz
#define ATTN_F 16384             // phase2: attn f32 [64][21] = 5376B
#define ATB_B  22528             // phase2.5-3: attn bf16 [64][128B] swz
#define FCQ_B  16384             // phase3+: f_cq/f_cc_hat bf16 [64][256B] swz
// Region C: 32768..38912
#define AC_B   32768             // A_c f32 [64][17] = 4352
#define FS_B   37120             // f_s_hat f32 [128]
#define SB_B   37632             // sb f32 [20]
#define SMEM_B 38912

__global__ __launch_bounds__(512, 8) void k2_fused(
    const float* __restrict__ f_c, const unsigned short* __restrict__ wdb,
    const unsigned short* __restrict__ wub,
    const unsigned short* __restrict__ kqb, const unsigned short* __restrict__ fwtb,
    const float* __restrict__ bc_down, const float* __restrict__ bc_up,
    const float* __restrict__ fbm,
    const float* __restrict__ ws, float* __restrict__ out) {
  __shared__ __align__(16) char smb[SMEM_B];
  float* sAttn = (float*)(smb + ATTN_F);
  float* sAc   = (float*)(smb + AC_B);
  float* sFs   = (float*)(smb + FS_B);
  float* sSb   = (float*)(smb + SB_B);

  const int t = threadIdx.x;            // 0..511
  const int row0 = blockIdx.x * ROWS;
  const int b = row0 >> 14;
  const int lane = t & 63, w = t >> 6;  // 8 waves
  const int l15 = lane & 15, l4 = lane >> 4;
  const float inv_sqrt_dl = 0.08838834764831843f;
  const f32x4 z4 = {0.f, 0.f, 0.f, 0.f};

  // staging coords
  const int sd_r  = t >> 3;             // 0..63   (FC: 1 int4/thread)
  const int sd_k8 = (t & 7) * 8;
  const int sd_swz = (sd_k8 * 2) ^ ((sd_r & 7) << 4);

  // ---------------- down GEMM: single-buffered, 2 barriers/chunk -----------
  f32x4 dacc[4];
  #pragma unroll
  for (int rt = 0; rt < 4; ++rt) dacc[rt] = z4;

  {
    const int ad = w * 16 + l15;                 // A row (d) for this wave
    const int aswz = (ad & 7) << 4;
    for (int ch = 0; ch < 8; ++ch) {
      const int kc = ch * 64;
      #pragma unroll
      for (int i = 0; i < 2; ++i) {
        const int idx = t + i*512;
        const int r = idx >> 3, k8 = (idx & 7) * 8;
        *(int4*)(smb + WD_B + r*128 + ((k8*2) ^ ((r & 7) << 4))) =
          *(const int4*)(wdb + (size_t)r*D_ + kc + k8);
      }
      {
        const float* src = f_c + (size_t)(row0 + sd_r)*D_ + kc + sd_k8;
        float4 v0 = *(const float4*)src;
        float4 v1 = *(const float4*)(src + 4);
        *(int4*)(smb + FC_B + sd_r*128 + sd_swz) = pack8(v0, v1);
      }
      __syncthreads();
      #pragma unroll
      for (int ks = 0; ks < 2; ++ks) {
        short8_t afrag = *(const short8_t*)(smb + WD_B + ad*128 +
                          ((ks*64 + l4*16) ^ aswz));
        #pragma unroll
        for (int rt = 0; rt < 4; ++rt) {
          const int rr = rt*16 + l15;
          short8_t bfrag = *(const short8_t*)(smb + FC_B + rr*128 +
                            ((ks*64 + l4*16) ^ ((rr & 7) << 4)));
          dacc[rt] = __builtin_amdgcn_mfma_f32_16x16x32_bf16(afrag, bfrag, dacc[rt], 0, 0, 0);
        }
      }
      __syncthreads();
    }
  }
  // writeout f_c_hat bf16 swz into region A (WD dead) + stage fs/sb
  {
    const int d0 = w*16 + l4*4;
    float4 bias = *(const float4*)(bc_down + d0);
    #pragma unroll
    for (int rt = 0; rt < 4; ++rt) {
      const int rr = rt*16 + l15;
      uint2 pw;
      pw.x = pkcvt(dacc[rt][0] + bias.x, dacc[rt][1] + bias.y);
      pw.y = pkcvt(dacc[rt][2] + bias.z, dacc[rt][3] + bias.w);
      *(uint2*)(smb + SFCH_B + rr*256 + ((d0*2) ^ ((rr & 7) << 4))) = pw;
    }
  }
  if (t < 32) *(float4*)(sFs + t*4) = *(const float4*)(ws + WS_FS + b*DL_ + t*4);
  if (t < L_) sSb[t] = ws[WS_SB + b*L_ + t];
  __syncthreads();

  // ---------------- phase2: scores via MFMA; kq frags direct-global --------
  {
    const int lt = w & 1, rt2 = w >> 1;       // l-tile(0..1), r-tile(0..3)
    const int arow = lt*16 + l15;
    const int brow = rt2*16 + l15;
    const unsigned short* kqrow = kqb + (size_t)(b*32 + arow)*DL_;
    f32x4 sacc = z4;
    #pragma unroll
    for (int ks = 0; ks < 4; ++ks) {
      short8_t af = *(const short8_t*)(kqrow + ks*32 + l4*8);
      short8_t bf = *(const short8_t*)(smb + SFCH_B + brow*256 +
                     ((ks*64 + l4*16) ^ ((brow & 7) << 4)));
      sacc = __builtin_amdgcn_mfma_f32_16x16x32_bf16(af, bf, sacc, 0, 0, 0);
    }
    const int r2 = rt2*16 + l15;
    #pragma unroll
    for (int reg = 0; reg < 4; ++reg) {
      const int lval = lt*16 + l4*4 + reg;
      if (lval < L_) sAttn[r2*21 + lval] = (sacc[reg] + sSb[lval]) * inv_sqrt_dl;
    }
  }
  __syncthreads();
  if (t < ROWS) {                              // softmax over L
    float* srow = sAttn + t*21;
    float m = -1e30f;
    for (int l = 0; l < L_; ++l) m = fmaxf(m, srow[l]);
    float sum = 0.f;
    for (int l = 0; l < L_; ++l) { float e = __expf(srow[l]-m); srow[l] = e; sum += e; }
    float inv = 1.f/sum;
    for (int l = 0; l < L_; ++l) srow[l] *= inv;
  }
  __syncthreads();
  { // pack attn -> bf16 [64][128B] swz at ATB (disjoint from sAttn)
    const int r = t >> 3, k8 = (t & 7) * 8;
    int4 v = {0,0,0,0};
    if (k8 < L_) {
      float vv[8];
      #pragma unroll
      for (int e = 0; e < 8; ++e) {
        const int l = k8 + e;
        vv[e] = (l < L_) ? sAttn[r*21 + l] : 0.f;
      }
      v.x = (int)pkcvt(vv[0], vv[1]);
      v.y = (int)pkcvt(vv[2], vv[3]);
      v.z = (int)pkcvt(vv[4], vv[5]);
      v.w = (int)pkcvt(vv[6], vv[7]);
    }
    *(int4*)(smb + ATB_B + r*128 + ((k8*2) ^ ((r & 7) << 4))) = v;
  }
  __syncthreads();
  // ---------------- phase3: f_caq via MFMA; fwT frags direct-global --------
  {
    f32x4 cacc[4];
    #pragma unroll
    for (int rt = 0; rt < 4; ++rt) cacc[rt] = z4;
    const int arow = w*16 + l15;               // fwT row (d)
    short8_t af = *(const short8_t*)(fwtb + (size_t)(b*DL_ + arow)*32 + l4*8);
    short8_t bf0 = *(const short8_t*)(smb + ATB_B + (0*16 + l15)*128 +
                    ((l4*16) ^ (((0*16 + l15) & 7) << 4)));
    short8_t bf1 = *(const short8_t*)(smb + ATB_B + (1*16 + l15)*128 +
                    ((l4*16) ^ (((1*16 + l15) & 7) << 4)));
    short8_t bf2 = *(const short8_t*)(smb + ATB_B + (2*16 + l15)*128 +
                    ((l4*16) ^ (((2*16 + l15) & 7) << 4)));
    short8_t bf3 = *(const short8_t*)(smb + ATB_B + (3*16 + l15)*128 +
                    ((l4*16) ^ (((3*16 + l15) & 7) << 4)));
    cacc[0] = __builtin_amdgcn_mfma_f32_16x16x32_bf16(af, bf0, cacc[0], 0, 0, 0);
    cacc[1] = __builtin_amdgcn_mfma_f32_16x16x32_bf16(af, bf1, cacc[1], 0, 0, 0);
    cacc[2] = __builtin_amdgcn_mfma_f32_16x16x32_bf16(af, bf2, cacc[2], 0, 0, 0);
    cacc[3] = __builtin_amdgcn_mfma_f32_16x16x32_bf16(af, bf3, cacc[3], 0, 0, 0);
    __syncthreads();            // all ATB reads complete before FCQ overwrite
    const int d0 = w*16 + l4*4;
    float4 fs4 = *(const float4*)(sFs + d0);
    #pragma unroll
    for (int rt = 0; rt < 4; ++rt) {
      const int r = rt*16 + l15;
      const int rs = (r & 7) << 4;
      ushort4 fh = *(const ushort4*)(smb + SFCH_B + r*256 + ((d0*2) ^ rs));
      uint2 pw;
      pw.x = pkcvt(b2f((short)fh.x)*(cacc[rt][0] + fs4.x),
                   b2f((short)fh.y)*(cacc[rt][1] + fs4.y));
      pw.y = pkcvt(b2f((short)fh.z)*(cacc[rt][2] + fs4.z),
                   b2f((short)fh.w)*(cacc[rt][3] + fs4.w));
      *(uint2*)(smb + FCQ_B + r*256 + ((d0*2) ^ rs)) = pw;
    }
  }
  __syncthreads();
  // ---------------- phase4: A_c Gram MFMA + wave-parallel softmax ----------
  if (w < 4) {
    const int zrow = w*16 + l15;
    f32x4 pacc = z4;
    #pragma unroll
    for (int ks = 0; ks < 4; ++ks) {
      short8_t fq = *(const short8_t*)(smb + FCQ_B + zrow*256 +
                     ((ks*64 + l4*16) ^ ((zrow & 7) << 4)));
      pacc = __builtin_amdgcn_mfma_f32_16x16x32_bf16(fq, fq, pacc, 0, 0, 0);
    }
    float p0[4], m[4], e[4], s[4];
    #pragma unroll
    for (int reg = 0; reg < 4; ++reg) p0[reg] = pacc[reg] * inv_sqrt_dl;
    #pragma unroll
    for (int reg = 0; reg < 4; ++reg) {
      m[reg] = p0[reg];
      m[reg] = fmaxf(m[reg], __shfl_xor(m[reg], 1));
      m[reg] = fmaxf(m[reg], __shfl_xor(m[reg], 2));
      m[reg] = fmaxf(m[reg], __shfl_xor(m[reg], 4));
      m[reg] = fmaxf(m[reg], __shfl_xor(m[reg], 8));
      e[reg] = __expf(p0[reg] - m[reg]);
      s[reg] = e[reg];
      s[reg] += __shfl_xor(s[reg], 1);
      s[reg] += __shfl_xor(s[reg], 2);
      s[reg] += __shfl_xor(s[reg], 4);
      s[reg] += __shfl_xor(s[reg], 8);
    }
    #pragma unroll
    for (int reg = 0; reg < 4; ++reg)
      sAc[(w*16 + l4*4 + reg)*17 + l15] = e[reg] / s[reg];
  }
  __syncthreads();
  // ---------------- phase5: f_cc_hat = A_c @ f_c_hat (VALU) -> FCQ ---------
  for (int p = t; p < ROWS*32; p += 512) {
    const int r = p >> 5, d4 = (p & 31)*4;
    const int g = r >> 4, z = r & 15;
    float ax = 0.f, ay = 0.f, az = 0.f, aw = 0.f;
    #pragma unroll
    for (int wq = 0; wq < 16; ++wq) {
      float a = sAc[(g*16+z)*17 + wq];
      const int fr = g*16 + wq;
      ushort4 fv = *(const ushort4*)(smb + SFCH_B + fr*256 + ((d4*2) ^ ((fr & 7) << 4)));
      ax += a*b2f((short)fv.x); ay += a*b2f((short)fv.y);
      az += a*b2f((short)fv.z); aw += a*b2f((short)fv.w);
    }
    uint2 pw;
    pw.x = pkcvt(ax, ay); pw.y = pkcvt(az, aw);
    *(uint2*)(smb + FCQ_B + r*256 + ((d4*2) ^ ((r & 7) << 4))) = pw;
  }
  __syncthreads();   // SFCH dead after this; WU may overwrite region A

  // ---------------- up GEMM: single-buffered, 2 barriers/chunk -------------
  {
    const int su_d = t >> 4;              // rows su_d, su_d+32
    const int su_k8 = (t & 15) * 8;
    const int su_swz = (su_k8 * 2) ^ ((su_d & 7) << 4);
    const int ad = (w & 3)*16 + l15;
    const int aswz = (ad & 7) << 4;
    const int rbase = (w >> 2) * 32;
    for (int ch = 0; ch < 8; ++ch) {
      { // stage Wu chunk [64][256B]: 2 int4/thread
        const unsigned short* up = wub + (size_t)ch*64*DL_ + su_k8;
        int4 u0 = *(const int4*)(up + (size_t)su_d * DL_);
        int4 u1 = *(const int4*)(up + (size_t)(su_d + 32) * DL_);
        *(int4*)(smb + WU_B + su_d * 256 + su_swz) = u0;
        *(int4*)(smb + WU_B + (su_d + 32) * 256 + su_swz) = u1;
      }
      __syncthreads();
      f32x4 uacc[2]; uacc[0] = z4; uacc[1] = z4;
      #pragma unroll
      for (int ks = 0; ks < 4; ++ks) {
        short8_t afrag = *(const short8_t*)(smb + WU_B + ad*256 +
                          ((ks*64 + l4*16) ^ aswz));
        #pragma unroll
        for (int cf = 0; cf < 2; ++cf) {
          const int rr = rbase + cf*16 + l15;
          short8_t bfrag = *(const short8_t*)(smb + FCQ_B + rr*256 +
                            ((ks*64 + l4*16) ^ ((rr & 7) << 4)));
          uacc[cf] = __builtin_amdgcn_mfma_f32_16x16x32_bf16(afrag, bfrag, uacc[cf], 0, 0, 0);
        }
      }
      {
        const int d0 = ch*64 + (w & 3)*16 + l4*4;
        float4 bias = *(const float4*)(bc_up + d0);
        #pragma unroll
        for (int cf = 0; cf < 2; ++cf) {
          const int grow = row0 + rbase + cf*16 + l15;
          const size_t obase = (size_t)grow * D_;
          float4 fb4 = *(const float4*)(fbm + ((size_t)(grow >> 4))*D_ + d0);
          float4 fc4 = *(const float4*)(f_c + obase + d0);
          float4 o;
          o.x = uacc[cf][0] + bias.x + fc4.x + fb4.x;
          o.y = uacc[cf][1] + bias.y + fc4.y + fb4.y;
          o.z = uacc[cf][2] + bias.z + fc4.z + fb4.z;
          o.w = uacc[cf][3] + bias.w + fc4.w + fb4.w;
          *(float4*)(out + obase + d0) = o;
        }
      }
      __syncthreads();
    }
  }
}

extern "C" void kernel_launch(void* const* d_in, const int* in_sizes, int n_in,
                              void* d_out, int out_size, void* d_ws, size_t ws_size,
                              hipStream_t stream) {
  (void)in_sizes; (void)n_in; (void)out_size; (void)ws_size;
  const float* f_c     = (const float*)d_in[0];
  const float* f_w     = (const float*)d_in[1];
  const float* f_s     = (const float*)d_in[2];
  const float* f_m     = (const float*)d_in[3];
  const float* Wc_down = (const float*)d_in[4];
  const float* bc_down = (const float*)d_in[5];
  const float* Ww      = (const float*)d_in[6];
  const float* bw      = (const float*)d_in[7];
  const float* Ws      = (const float*)d_in[8];
  const float* bs      = (const float*)d_in[9];
  const float* Wq      = (const float*)d_in[10];
  const float* bq      = (const float*)d_in[11];
  const float* Wk      = (const float*)d_in[12];
  const float* bk      = (const float*)d_in[13];
  const float* Wc_up   = (const float*)d_in[14];
  const float* bc_up   = (const float*)d_in[15];
  float* out = (float*)d_out;
  float* wsf = (float*)d_ws;
  unsigned short* wdb  = (unsigned short*)(wsf + WS_WDB);
  unsigned short* wub  = (unsigned short*)(wsf + WS_WUB);
  unsigned short* kqb  = (unsigned short*)(wsf + WS_KQB);
  unsigned short* fwtb = (unsigned short*)(wsf + WS_FWT);
  float* fbm = wsf + WS_FBM;

  hipLaunchKernelGGL(k0_prep, dim3(4096 + B_*L_), dim3(256), 0, stream,
                     Wc_down, Wc_up, f_m, f_s, f_w,
                     Ww, bw, Ws, bs, Wq, bq, Wk, bk,
                     wdb, wub, kqb, fwtb, fbm, wsf);
  hipLaunchKernelGGL(k2_fused, dim3(M_/ROWS), dim3(512), 0, stream,
                     f_c, wdb, wub, kqb, fwtb, bc_down, bc_up, fbm, wsf, out);
}

// Round 19
// 221.132 us; speedup vs baseline: 1.5738x; 1.0524x over previous
//
#include <hip/hip_runtime.h>
#include <hip/hip_bf16.h>
#include <math.h>

#define B_ 8
#define T1_ 32
#define T2_ 32
#define T3_ 16
#define D_ 512
#define L_ 20
#define DL_ 128
#define M_ (B_*T1_*T2_*T3_)   // 131072
#define ROWS 64               // rows per block

// workspace layout (float offsets)
#define WS_FS   0        // B*DL f32 = 1024
#define WS_SB   1024     // B*L f32 = 160
#define WS_WDB  1184     // Wc_down bf16 [128][512]
#define WS_WUB  33952    // Wc_up bf16 [512][128]
#define WS_KQB  66720    // kq bf16 [B][32][128] (rows>=20 zero)
#define WS_FWT  83104    // fw^T bf16 [B][128][32] (cols>=20 zero)
#define WS_FBM  99488    // fbar_m f32 [B][T1][T2][D] = 4194304

typedef __attribute__((ext_vector_type(8))) short short8_t;
typedef __attribute__((ext_vector_type(4))) float f32x4;

__device__ __forceinline__ unsigned pkcvt(float a, float b) {
  float2 v; v.x = a; v.y = b;
  __hip_bfloat162 h = __float22bfloat162_rn(v);
  unsigned r;
  __builtin_memcpy(&r, &h, sizeof(r));
  return r;
}
__device__ __forceinline__ unsigned short f2b(float f) {
  __hip_bfloat16 h = __float2bfloat16(f);
  unsigned short r;
  __builtin_memcpy(&r, &h, sizeof(r));
  return r;
}
__device__ __forceinline__ float b2f(short s) {
  return __uint_as_float(((unsigned)(unsigned short)s) << 16);
}
__device__ __forceinline__ int4 pack8(float4 a, float4 b) {
  int4 p;
  p.x = (int)pkcvt(a.x, a.y); p.y = (int)pkcvt(a.z, a.w);
  p.z = (int)pkcvt(b.x, b.y); p.w = (int)pkcvt(b.z, b.w);
  return p;
}

// ---------------------------------------------------------------------------
// K0: fbar_m gate (all threads) + weight fp32->bf16 + kqb/fwtb zeroing
// ---------------------------------------------------------------------------
__global__ __launch_bounds__(256) void k0_prep(
    const float* __restrict__ Wd, const float* __restrict__ Wu,
    const float* __restrict__ f_m, const float* __restrict__ f_s,
    unsigned short* __restrict__ wdb, unsigned short* __restrict__ wub,
    unsigned short* __restrict__ kqb, unsigned short* __restrict__ fwtb,
    float* __restrict__ fbm) {
  int i = blockIdx.x * 256 + threadIdx.x;      // 0..1048575
  {
    float4 m = ((const float4*)f_m)[i];
    int e = i * 4; int b = e >> 19; int d0 = e & 511;
    float4 s = *(const float4*)(f_s + (size_t)b*D_ + d0);
    float4 g;
    g.x = m.x/(1.f + __expf(-m.x*s.x));
    g.y = m.y/(1.f + __expf(-m.y*s.y));
    g.z = m.z/(1.f + __expf(-m.z*s.z));
    g.w = m.w/(1.f + __expf(-m.w*s.w));
    ((float4*)fbm)[i] = g;
  }
  if (i < 16384) {
    float4 v = ((const float4*)Wd)[i];
    uint2 h; h.x = pkcvt(v.x, v.y); h.y = pkcvt(v.z, v.w);
    ((uint2*)wdb)[i] = h;
  } else if (i < 32768) {
    int q = i - 16384;
    float4 v = ((const float4*)Wu)[q];
    uint2 h; h.x = pkcvt(v.x, v.y); h.y = pkcvt(v.z, v.w);
    ((uint2*)wub)[q] = h;
  }
  if (i < 32768) { kqb[i] = 0; fwtb[i] = 0; }
}

// ---------------------------------------------------------------------------
// K1: tiny projections -> kqb (bf16), fwtb (bf16 transposed), fs/sb (f32)
// ---------------------------------------------------------------------------
__global__ __launch_bounds__(128) void k1_small(
    const float* __restrict__ f_w, const float* __restrict__ f_s,
    const float* __restrict__ Ww, const float* __restrict__ bw,
    const float* __restrict__ Ws, const float* __restrict__ bs,
    const float* __restrict__ Wq, const float* __restrict__ bq,
    const float* __restrict__ Wk, const float* __restrict__ bk,
    unsigned short* __restrict__ kqb, unsigned short* __restrict__ fwtb,
    float* __restrict__ ws) {
  const int bl = blockIdx.x;
  const int b = bl / L_, l = bl % L_;
  const int d = threadIdx.x;
  __shared__ float s_fw[DL_];
  __shared__ float s_k[DL_];
  {
    const float* x = f_w + (size_t)(b*L_+l)*D_;
    const float* w = Ww + (size_t)d*D_;
    float acc = 0.f;
    for (int i = 0; i < D_; i += 4)
      acc += x[i]*w[i] + x[i+1]*w[i+1] + x[i+2]*w[i+2] + x[i+3]*w[i+3];
    acc += bw[d];
    s_fw[d] = acc;
    fwtb[((size_t)(b*DL_ + d))*32 + l] = f2b(acc);
  }
  if (l == 0) {
    const float* x = f_s + (size_t)b*D_;
    const float* w = Ws + (size_t)d*D_;
    float acc = 0.f;
    for (int i = 0; i < D_; i += 4)
      acc += x[i]*w[i] + x[i+1]*w[i+1] + x[i+2]*w[i+2] + x[i+3]*w[i+3];
    ws[WS_FS + b*DL_ + d] = acc + bs[d];
  }
  __syncthreads();
  {
    const float* w = Wk + (size_t)d*DL_;
    float acc = 0.f;
    for (int i = 0; i < DL_; ++i) acc += s_fw[i]*w[i];
    s_k[d] = acc + bk[d];
  }
  __syncthreads();
  {
    float acc = 0.f;
    for (int c = 0; c < DL_; ++c) acc += s_k[c] * Wq[c*DL_ + d];
    kqb[((size_t)(b*32 + l))*DL_ + d] = f2b(acc);
  }
  if (d == 0) {
    float acc = 0.f;
    for (int c = 0; c < DL_; ++c) acc += bq[c]*s_k[c];
    ws[WS_SB + b*L_ + l] = acc;
  }
}

// ---------------------------------------------------------------------------
// K2: fused per 64-row tile, 512 threads (8 waves). 38 KB LDS -> 4 blocks/CU
// (32 waves/CU). Verified best structure (221.6 us total).
// ---------------------------------------------------------------------------
// Region A: 0..16384
#define WD_B   0                 // down: Wd chunk [128][128B] swz
#define SFCH_B 0                 // after down: f_c_hat bf16 [64][256B] swz
#define WU_B   0                 // up: Wu chunk [64][256B] swz (after ph5)
// Region B: 16384..32768
#define FC_B   16384             // down: f_c chunk [64][128B] swz
#define ATTN_F 16384             // phase2: attn f32 [64][21] = 5376B
#define ATB_B  22528             // phase2.5-3: attn bf16 [64][128B] swz
#define FCQ_B  16384             // phase3+: f_cq/f_cc_hat bf16 [64][256B] swz
// Region C: 32768..38912
#define AC_B   32768             // A_c f32 [64][17] = 4352
#define FS_B   37120             // f_s_hat f32 [128]
#define SB_B   37632             // sb f32 [20]
#define SMEM_B 38912

__global__ __launch_bounds__(512, 8) void k2_fused(
    const float* __restrict__ f_c, const unsigned short* __restrict__ wdb,
    const unsigned short* __restrict__ wub,
    const unsigned short* __restrict__ kqb, const unsigned short* __restrict__ fwtb,
    const float* __restrict__ bc_down, const float* __restrict__ bc_up,
    const float* __restrict__ fbm,
    const float* __restrict__ ws, float* __restrict__ out) {
  __shared__ __align__(16) char smb[SMEM_B];
  float* sAttn = (float*)(smb + ATTN_F);
  float* sAc   = (float*)(smb + AC_B);
  float* sFs   = (float*)(smb + FS_B);
  float* sSb   = (float*)(smb + SB_B);

  const int t = threadIdx.x;            // 0..511
  const int row0 = blockIdx.x * ROWS;
  const int b = row0 >> 14;
  const int lane = t & 63, w = t >> 6;  // 8 waves
  const int l15 = lane & 15, l4 = lane >> 4;
  const float inv_sqrt_dl = 0.08838834764831843f;
  const f32x4 z4 = {0.f, 0.f, 0.f, 0.f};

  // staging coords
  const int sd_r  = t >> 3;             // 0..63   (FC: 1 int4/thread)
  const int sd_k8 = (t & 7) * 8;
  const int sd_swz = (sd_k8 * 2) ^ ((sd_r & 7) << 4);

  // ---------------- down GEMM: single-buffered, 2 barriers/chunk -----------
  f32x4 dacc[4];
  #pragma unroll
  for (int rt = 0; rt < 4; ++rt) dacc[rt] = z4;

  {
    const int ad = w * 16 + l15;                 // A row (d) for this wave
    const int aswz = (ad & 7) << 4;
    for (int ch = 0; ch < 8; ++ch) {
      const int kc = ch * 64;
      #pragma unroll
      for (int i = 0; i < 2; ++i) {
        const int idx = t + i*512;
        const int r = idx >> 3, k8 = (idx & 7) * 8;
        *(int4*)(smb + WD_B + r*128 + ((k8*2) ^ ((r & 7) << 4))) =
          *(const int4*)(wdb + (size_t)r*D_ + kc + k8);
      }
      {
        const float* src = f_c + (size_t)(row0 + sd_r)*D_ + kc + sd_k8;
        float4 v0 = *(const float4*)src;
        float4 v1 = *(const float4*)(src + 4);
        *(int4*)(smb + FC_B + sd_r*128 + sd_swz) = pack8(v0, v1);
      }
      __syncthreads();
      #pragma unroll
      for (int ks = 0; ks < 2; ++ks) {
        short8_t afrag = *(const short8_t*)(smb + WD_B + ad*128 +
                          ((ks*64 + l4*16) ^ aswz));
        #pragma unroll
        for (int rt = 0; rt < 4; ++rt) {
          const int rr = rt*16 + l15;
          short8_t bfrag = *(const short8_t*)(smb + FC_B + rr*128 +
                            ((ks*64 + l4*16) ^ ((rr & 7) << 4)));
          dacc[rt] = __builtin_amdgcn_mfma_f32_16x16x32_bf16(afrag, bfrag, dacc[rt], 0, 0, 0);
        }
      }
      __syncthreads();
    }
  }
  // writeout f_c_hat bf16 swz into region A (WD dead) + stage fs/sb
  {
    const int d0 = w*16 + l4*4;
    float4 bias = *(const float4*)(bc_down + d0);
    #pragma unroll
    for (int rt = 0; rt < 4; ++rt) {
      const int rr = rt*16 + l15;
      uint2 pw;
      pw.x = pkcvt(dacc[rt][0] + bias.x, dacc[rt][1] + bias.y);
      pw.y = pkcvt(dacc[rt][2] + bias.z, dacc[rt][3] + bias.w);
      *(uint2*)(smb + SFCH_B + rr*256 + ((d0*2) ^ ((rr & 7) << 4))) = pw;
    }
  }
  if (t < 32) *(float4*)(sFs + t*4) = *(const float4*)(ws + WS_FS + b*DL_ + t*4);
  if (t < L_) sSb[t] = ws[WS_SB + b*L_ + t];
  __syncthreads();

  // ---------------- phase2: scores via MFMA; kq frags direct-global --------
  {
    const int lt = w & 1, rt2 = w >> 1;       // l-tile(0..1), r-tile(0..3)
    const int arow = lt*16 + l15;
    const int brow = rt2*16 + l15;
    const unsigned short* kqrow = kqb + (size_t)(b*32 + arow)*DL_;
    f32x4 sacc = z4;
    #pragma unroll
    for (int ks = 0; ks < 4; ++ks) {
      short8_t af = *(const short8_t*)(kqrow + ks*32 + l4*8);
      short8_t bf = *(const short8_t*)(smb + SFCH_B + brow*256 +
                     ((ks*64 + l4*16) ^ ((brow & 7) << 4)));
      sacc = __builtin_amdgcn_mfma_f32_16x16x32_bf16(af, bf, sacc, 0, 0, 0);
    }
    const int r2 = rt2*16 + l15;
    #pragma unroll
    for (int reg = 0; reg < 4; ++reg) {
      const int lval = lt*16 + l4*4 + reg;
      if (lval < L_) sAttn[r2*21 + lval] = (sacc[reg] + sSb[lval]) * inv_sqrt_dl;
    }
  }
  __syncthreads();
  if (t < ROWS) {                              // softmax over L
    float* srow = sAttn + t*21;
    float m = -1e30f;
    for (int l = 0; l < L_; ++l) m = fmaxf(m, srow[l]);
    float sum = 0.f;
    for (int l = 0; l < L_; ++l) { float e = __expf(srow[l]-m); srow[l] = e; sum += e; }
    float inv = 1.f/sum;
    for (int l = 0; l < L_; ++l) srow[l] *= inv;
  }
  __syncthreads();
  { // pack attn -> bf16 [64][128B] swz at ATB (disjoint from sAttn)
    const int r = t >> 3, k8 = (t & 7) * 8;
    int4 v = {0,0,0,0};
    if (k8 < L_) {
      float vv[8];
      #pragma unroll
      for (int e = 0; e < 8; ++e) {
        const int l = k8 + e;
        vv[e] = (l < L_) ? sAttn[r*21 + l] : 0.f;
      }
      v.x = (int)pkcvt(vv[0], vv[1]);
      v.y = (int)pkcvt(vv[2], vv[3]);
      v.z = (int)pkcvt(vv[4], vv[5]);
      v.w = (int)pkcvt(vv[6], vv[7]);
    }
    *(int4*)(smb + ATB_B + r*128 + ((k8*2) ^ ((r & 7) << 4))) = v;
  }
  __syncthreads();
  // ---------------- phase3: f_caq via MFMA; fwT frags direct-global --------
  {
    f32x4 cacc[4];
    #pragma unroll
    for (int rt = 0; rt < 4; ++rt) cacc[rt] = z4;
    const int arow = w*16 + l15;               // fwT row (d)
    short8_t af = *(const short8_t*)(fwtb + (size_t)(b*DL_ + arow)*32 + l4*8);
    short8_t bf0 = *(const short8_t*)(smb + ATB_B + (0*16 + l15)*128 +
                    ((l4*16) ^ (((0*16 + l15) & 7) << 4)));
    short8_t bf1 = *(const short8_t*)(smb + ATB_B + (1*16 + l15)*128 +
                    ((l4*16) ^ (((1*16 + l15) & 7) << 4)));
    short8_t bf2 = *(const short8_t*)(smb + ATB_B + (2*16 + l15)*128 +
                    ((l4*16) ^ (((2*16 + l15) & 7) << 4)));
    short8_t bf3 = *(const short8_t*)(smb + ATB_B + (3*16 + l15)*128 +
                    ((l4*16) ^ (((3*16 + l15) & 7) << 4)));
    cacc[0] = __builtin_amdgcn_mfma_f32_16x16x32_bf16(af, bf0, cacc[0], 0, 0, 0);
    cacc[1] = __builtin_amdgcn_mfma_f32_16x16x32_bf16(af, bf1, cacc[1], 0, 0, 0);
    cacc[2] = __builtin_amdgcn_mfma_f32_16x16x32_bf16(af, bf2, cacc[2], 0, 0, 0);
    cacc[3] = __builtin_amdgcn_mfma_f32_16x16x32_bf16(af, bf3, cacc[3], 0, 0, 0);
    __syncthreads();            // all ATB reads complete before FCQ overwrite
    const int d0 = w*16 + l4*4;
    float4 fs4 = *(const float4*)(sFs + d0);
    #pragma unroll
    for (int rt = 0; rt < 4; ++rt) {
      const int r = rt*16 + l15;
      const int rs = (r & 7) << 4;
      ushort4 fh = *(const ushort4*)(smb + SFCH_B + r*256 + ((d0*2) ^ rs));
      uint2 pw;
      pw.x = pkcvt(b2f((short)fh.x)*(cacc[rt][0] + fs4.x),
                   b2f((short)fh.y)*(cacc[rt][1] + fs4.y));
      pw.y = pkcvt(b2f((short)fh.z)*(cacc[rt][2] + fs4.z),
                   b2f((short)fh.w)*(cacc[rt][3] + fs4.w));
      *(uint2*)(smb + FCQ_B + r*256 + ((d0*2) ^ rs)) = pw;
    }
  }
  __syncthreads();
  // ---------------- phase4: A_c Gram MFMA + wave-parallel softmax ----------
  if (w < 4) {
    const int zrow = w*16 + l15;
    f32x4 pacc = z4;
    #pragma unroll
    for (int ks = 0; ks < 4; ++ks) {
      short8_t fq = *(const short8_t*)(smb + FCQ_B + zrow*256 +
                     ((ks*64 + l4*16) ^ ((zrow & 7) << 4)));
      pacc = __builtin_amdgcn_mfma_f32_16x16x32_bf16(fq, fq, pacc, 0, 0, 0);
    }
    float p0[4], m[4], e[4], s[4];
    #pragma unroll
    for (int reg = 0; reg < 4; ++reg) p0[reg] = pacc[reg] * inv_sqrt_dl;
    #pragma unroll
    for (int reg = 0; reg < 4; ++reg) {
      m[reg] = p0[reg];
      m[reg] = fmaxf(m[reg], __shfl_xor(m[reg], 1));
      m[reg] = fmaxf(m[reg], __shfl_xor(m[reg], 2));
      m[reg] = fmaxf(m[reg], __shfl_xor(m[reg], 4));
      m[reg] = fmaxf(m[reg], __shfl_xor(m[reg], 8));
      e[reg] = __expf(p0[reg] - m[reg]);
      s[reg] = e[reg];
      s[reg] += __shfl_xor(s[reg], 1);
      s[reg] += __shfl_xor(s[reg], 2);
      s[reg] += __shfl_xor(s[reg], 4);
      s[reg] += __shfl_xor(s[reg], 8);
    }
    #pragma unroll
    for (int reg = 0; reg < 4; ++reg)
      sAc[(w*16 + l4*4 + reg)*17 + l15] = e[reg] / s[reg];
  }
  __syncthreads();
  // ---------------- phase5: f_cc_hat = A_c @ f_c_hat (VALU) -> FCQ ---------
  for (int p = t; p < ROWS*32; p += 512) {
    const int r = p >> 5, d4 = (p & 31)*4;
    const int g = r >> 4, z = r & 15;
    float ax = 0.f, ay = 0.f, az = 0.f, aw = 0.f;
    #pragma unroll
    for (int wq = 0; wq < 16; ++wq) {
      float a = sAc[(g*16+z)*17 + wq];
      const int fr = g*16 + wq;
      ushort4 fv = *(const ushort4*)(smb + SFCH_B + fr*256 + ((d4*2) ^ ((fr & 7) << 4)));
      ax += a*b2f((short)fv.x); ay += a*b2f((short)fv.y);
      az += a*b2f((short)fv.z); aw += a*b2f((short)fv.w);
    }
    uint2 pw;
    pw.x = pkcvt(ax, ay); pw.y = pkcvt(az, aw);
    *(uint2*)(smb + FCQ_B + r*256 + ((d4*2) ^ ((r & 7) << 4))) = pw;
  }
  __syncthreads();   // SFCH dead after this; WU may overwrite region A

  // ---------------- up GEMM: single-buffered, 2 barriers/chunk -------------
  {
    const int su_d = t >> 4;              // rows su_d, su_d+32
    const int su_k8 = (t & 15) * 8;
    const int su_swz = (su_k8 * 2) ^ ((su_d & 7) << 4);
    const int ad = (w & 3)*16 + l15;
    const int aswz = (ad & 7) << 4;
    const int rbase = (w >> 2) * 32;
    for (int ch = 0; ch < 8; ++ch) {
      { // stage Wu chunk [64][256B]: 2 int4/thread
        const unsigned short* up = wub + (size_t)ch*64*DL_ + su_k8;
        int4 u0 = *(const int4*)(up + (size_t)su_d * DL_);
        int4 u1 = *(const int4*)(up + (size_t)(su_d + 32) * DL_);
        *(int4*)(smb + WU_B + su_d * 256 + su_swz) = u0;
        *(int4*)(smb + WU_B + (su_d + 32) * 256 + su_swz) = u1;
      }
      __syncthreads();
      f32x4 uacc[2]; uacc[0] = z4; uacc[1] = z4;
      #pragma unroll
      for (int ks = 0; ks < 4; ++ks) {
        short8_t afrag = *(const short8_t*)(smb + WU_B + ad*256 +
                          ((ks*64 + l4*16) ^ aswz));
        #pragma unroll
        for (int cf = 0; cf < 2; ++cf) {
          const int rr = rbase + cf*16 + l15;
          short8_t bfrag = *(const short8_t*)(smb + FCQ_B + rr*256 +
                            ((ks*64 + l4*16) ^ ((rr & 7) << 4)));
          uacc[cf] = __builtin_amdgcn_mfma_f32_16x16x32_bf16(afrag, bfrag, uacc[cf], 0, 0, 0);
        }
      }
      {
        const int d0 = ch*64 + (w & 3)*16 + l4*4;
        float4 bias = *(const float4*)(bc_up + d0);
        #pragma unroll
        for (int cf = 0; cf < 2; ++cf) {
          const int grow = row0 + rbase + cf*16 + l15;
          const size_t obase = (size_t)grow * D_;
          float4 fb4 = *(const float4*)(fbm + ((size_t)(grow >> 4))*D_ + d0);
          float4 fc4 = *(const float4*)(f_c + obase + d0);
          float4 o;
          o.x = uacc[cf][0] + bias.x + fc4.x + fb4.x;
          o.y = uacc[cf][1] + bias.y + fc4.y + fb4.y;
          o.z = uacc[cf][2] + bias.z + fc4.z + fb4.z;
          o.w = uacc[cf][3] + bias.w + fc4.w + fb4.w;
          *(float4*)(out + obase + d0) = o;
        }
      }
      __syncthreads();
    }
  }
}

extern "C" void kernel_launch(void* const* d_in, const int* in_sizes, int n_in,
                              void* d_out, int out_size, void* d_ws, size_t ws_size,
                              hipStream_t stream) {
  (void)in_sizes; (void)n_in; (void)out_size; (void)ws_size;
  const float* f_c     = (const float*)d_in[0];
  const float* f_w     = (const float*)d_in[1];
  const float* f_s     = (const float*)d_in[2];
  const float* f_m     = (const float*)d_in[3];
  const float* Wc_down = (const float*)d_in[4];
  const float* bc_down = (const float*)d_in[5];
  const float* Ww      = (const float*)d_in[6];
  const float* bw      = (const float*)d_in[7];
  const float* Ws      = (const float*)d_in[8];
  const float* bs      = (const float*)d_in[9];
  const float* Wq      = (const float*)d_in[10];
  const float* bq      = (const float*)d_in[11];
  const float* Wk      = (const float*)d_in[12];
  const float* bk      = (const float*)d_in[13];
  const float* Wc_up   = (const float*)d_in[14];
  const float* bc_up   = (const float*)d_in[15];
  float* out = (float*)d_out;
  float* wsf = (float*)d_ws;
  unsigned short* wdb  = (unsigned short*)(wsf + WS_WDB);
  unsigned short* wub  = (unsigned short*)(wsf + WS_WUB);
  unsigned short* kqb  = (unsigned short*)(wsf + WS_KQB);
  unsigned short* fwtb = (unsigned short*)(wsf + WS_FWT);
  float* fbm = wsf + WS_FBM;

  hipLaunchKernelGGL(k0_prep, dim3(4096), dim3(256), 0, stream,
                     Wc_down, Wc_up, f_m, f_s, wdb, wub, kqb, fwtb, fbm);
  hipLaunchKernelGGL(k1_small, dim3(B_*L_), dim3(128), 0, stream,
                     f_w, f_s, Ww, bw, Ws, bs, Wq, bq, Wk, bk, kqb, fwtb, wsf);
  hipLaunchKernelGGL(k2_fused, dim3(M_/ROWS), dim3(512), 0, stream,
                     f_c, wdb, wub, kqb, fwtb, bc_down, bc_up, fbm, wsf, out);
}